// Round 4
// baseline (90.370 us; speedup 1.0000x reference)
//
#include <hip/hip_runtime.h>
#include <hip/hip_bf16.h>
#include <math.h>

// Problem constants (match reference setup_inputs)
#define NN 4096
#define MM 128
#define QQ 64
#define DD 128
#define CC (MM * QQ)          // 8192 gemm "columns" (flattened m,q)

typedef short bf16x8 __attribute__((ext_vector_type(8)));  // 8 bf16 = 4 VGPRs
typedef float f32x4  __attribute__((ext_vector_type(4)));

static __device__ inline unsigned short f2bf(float f) {
    __hip_bfloat16 h = __float2bfloat16(f);
    return *reinterpret_cast<unsigned short*>(&h);
}

// ---- pre-kernel: fp32->bf16 convert + exact fp32 squared norms ----
__global__ __launch_bounds__(256)
void prep_kernel(const float* __restrict__ A, const float* __restrict__ B,
                 unsigned short* __restrict__ Abf, unsigned short* __restrict__ Bbf,
                 float* __restrict__ a2, float* __restrict__ b2)
{
    const int row  = blockIdx.x * 4 + (threadIdx.x >> 6);   // 0..12287
    const int lane = threadIdx.x & 63;
    const float* src;
    unsigned short* dst;
    float* nrm;
    if (row < NN) { src = A + (size_t)row * DD; dst = Abf + (size_t)row * DD; nrm = a2 + row; }
    else {
        int r = row - NN;
        src = B + (size_t)r * DD; dst = Bbf + (size_t)r * DD; nrm = b2 + r;
    }
    float2 v = ((const float2*)src)[lane];
    ushort2 u; u.x = f2bf(v.x); u.y = f2bf(v.y);
    ((ushort2*)dst)[lane] = u;
    float s = v.x * v.x + v.y * v.y;
    #pragma unroll
    for (int off = 32; off > 0; off >>= 1) s += __shfl_down(s, off);
    if (lane == 0) *nrm = s;
}

// ---- main: bf16 MFMA (one-shot K=128), 128 rows x 64 cols per block = ONE m ----
// LDS rows 0..127 = A tile, 128..191 = B tile (one m's 64 q rows). Pad-free for
// global_load_lds; conflicts broken by XOR chunk swizzle (cb ^= row&7).
// 49 KB LDS -> 3 blocks/CU = 12 waves. dens written TRANSPOSED: dpc[m][n].
__global__ __launch_bounds__(256, 3)
void kde_mfma_kernel(const unsigned short* __restrict__ Abf,  // [NN][DD] bf16
                     const unsigned short* __restrict__ Bbf,  // [CC][DD] bf16
                     const float* __restrict__ var,
                     const float* __restrict__ a2w,           // [NN]
                     const float* __restrict__ b2w,           // [CC]
                     float* __restrict__ dpc)                 // [MM][NN] transposed!
{
    __shared__ unsigned short Tile[192 * DD];   // 48 KB
    __shared__ float a2s[128];
    __shared__ float b2s[64];

    // XCD swizzle: XCD x owns m in [16x, 16x+16)
    const int lin = blockIdx.x;                // 0..4095
    const int xcd = lin & 7;
    const int loc = lin >> 3;                  // 0..511
    const int m   = (xcd << 4) | (loc >> 5);   // 0..127
    const int bx  = loc & 31;
    const int n0  = bx * 128;
    const int c0  = m * QQ;                    // this block's 64 cols = one m

    const int t    = threadIdx.x;
    const int w    = t >> 6;
    const int lane = t & 63;

    // ---- async staging: 3072 16B chunks, 12 instrs/wave ----
    const unsigned short* Ab = Abf + (size_t)n0 * DD;
    const unsigned short* Bb = Bbf + (size_t)c0 * DD;
    #pragma unroll
    for (int i = 0; i < 12; ++i) {
        const int slot = w * 768 + i * 64 + lane;    // 0..3071
        const int r    = slot >> 4;                  // LDS row 0..191
        const int cb   = slot & 15;
        const int scb  = cb ^ (r & 7);               // swizzled source chunk
        const unsigned short* g = (r < 128) ? (Ab + r * DD + scb * 8)
                                            : (Bb + (r - 128) * DD + scb * 8);
        unsigned short* lbase = &Tile[(w * 768 + i * 64) * 8];   // wave-uniform
        __builtin_amdgcn_global_load_lds(
            (const __attribute__((address_space(1))) unsigned int*)g,
            (__attribute__((address_space(3))) unsigned int*)lbase,
            16, 0, 0);
    }
    if (t < 128)            a2s[t]       = a2w[n0 + t];
    else if (t < 192)       b2s[t - 128] = b2w[c0 + (t - 128)];
    __syncthreads();   // drains vmcnt(0) incl. global_load_lds

    // ---- MFMA: wave w -> rows w*32..w*32+31, all 64 cols ----
    const int l15   = lane & 15;
    const int q     = lane >> 4;
    const int xr    = l15 & 7;
    const int rbase = w * 32;

    f32x4 acc[2][4] = {};
    #pragma unroll
    for (int ks = 0; ks < 4; ++ks) {           // K = 4 * 32
        const int off = ((ks * 4 + q) ^ xr) * 8;
        bf16x8 af[2], bf[4];
        #pragma unroll
        for (int i2 = 0; i2 < 2; ++i2)
            af[i2] = *(const bf16x8*)&Tile[(rbase + i2 * 16 + l15) * DD + off];
        #pragma unroll
        for (int j = 0; j < 4; ++j)
            bf[j] = *(const bf16x8*)&Tile[(128 + j * 16 + l15) * DD + off];
        #pragma unroll
        for (int i2 = 0; i2 < 2; ++i2)
            #pragma unroll
            for (int j = 0; j < 4; ++j)
                acc[i2][j] = __builtin_amdgcn_mfma_f32_16x16x32_bf16(
                                 af[i2], bf[j], acc[i2][j], 0, 0, 0);
    }

    // ---- epilogue: exp + Q-partials into wave-private LDS scratch ----
    // Scratch = this wave's own A rows (only this wave ever read them).
    const float hinv = 0.5f / var[0];
    float* S = (float*)&Tile[rbase * DD];      // 8 KB region, use 32x20 floats
    #pragma unroll
    for (int i2 = 0; i2 < 2; ++i2) {
        #pragma unroll
        for (int reg = 0; reg < 4; ++reg) {
            const int ri = i2 * 16 + q * 4 + reg;          // 0..31
            const float a2 = a2s[rbase + ri];
            float p = 0.f;
            #pragma unroll
            for (int j = 0; j < 4; ++j) {
                const float b2 = b2s[j * 16 + l15];
                p += __expf((2.f * acc[i2][j][reg] - a2 - b2) * hinv);
            }
            S[ri * 20 + l15] = p;              // stride 20 -> 2-way banks (free)
        }
    }
    __syncthreads();                           // order writes before cross-lane reads

    if (lane < 32) {
        const float* Sr = S + lane * 20;       // 80B-aligned -> b128 ok
        f32x4 s0 = *(const f32x4*)&Sr[0];
        f32x4 s1 = *(const f32x4*)&Sr[4];
        f32x4 s2 = *(const f32x4*)&Sr[8];
        f32x4 s3 = *(const f32x4*)&Sr[12];
        f32x4 ss = s0 + s1 + s2 + s3;
        const float dens = ss[0] + ss[1] + ss[2] + ss[3];
        // transposed, coalesced: 32 consecutive floats per wave
        dpc[(size_t)m * NN + n0 + rbase + lane] = dens;
    }
}

// ---- normalize: out[n,m] = dpc[m,n] / (sum_m dpc[:,n] + 1e-10) ----
__global__ __launch_bounds__(128)
void kde_norm_kernel(const float* __restrict__ dpc, float* __restrict__ out)
{
    const int n = blockIdx.x;
    const int t = threadIdx.x;                 // = m, 0..127
    const float v = dpc[(size_t)t * NN + n];   // strided gather, L2-resident (2MB)
    float s = v;
    #pragma unroll
    for (int off = 32; off > 0; off >>= 1) s += __shfl_down(s, off);
    __shared__ float wsum[2];
    if ((t & 63) == 0) wsum[t >> 6] = s;
    __syncthreads();
    const float tot = wsum[0] + wsum[1];
    out[(size_t)n * MM + t] = v / (tot + 1e-10f);
}

extern "C" void kernel_launch(void* const* d_in, const int* in_sizes, int n_in,
                              void* d_out, int out_size, void* d_ws, size_t ws_size,
                              hipStream_t stream) {
    const float* A   = (const float*)d_in[0];   // [4096][128]
    const float* B   = (const float*)d_in[1];   // [128][64][128] = [8192][128]
    const float* var = (const float*)d_in[2];   // [1]
    float* out = (float*)d_out;                 // [4096][128]

    unsigned short* Abf = (unsigned short*)d_ws;        // 1 MB
    unsigned short* Bbf = Abf + (size_t)NN * DD;        // 2 MB
    float* a2  = (float*)(Bbf + (size_t)CC * DD);       // 16 KB
    float* b2  = a2 + NN;                               // 32 KB
    float* dpc = b2 + CC;                               // 2 MB, [MM][NN]

    prep_kernel<<<(NN + CC) / 4, 256, 0, stream>>>(A, B, Abf, Bbf, a2, b2);
    kde_mfma_kernel<<<4096, 256, 0, stream>>>(Abf, Bbf, var, a2, b2, dpc);
    kde_norm_kernel<<<NN, 128, 0, stream>>>(dpc, out);
}